// Round 7
// baseline (164.692 us; speedup 1.0000x reference)
//
#include <hip/hip_runtime.h>

#define NPRED  4000
#define NGROUP 1000   // NPRED / 4
#define NGT    300
#define NGTH   150    // NGT / 2 (gts per block = 2)
#define NCLS   80
#define TOPKK  13
#define NCHUNK 125    // NPRED / 32 (exact)

typedef unsigned long long u64;

// Fast-math ops: ordering-safe — pass threshold is 6.0; only discrete
// selections matter. NOTE (r9/r13 lesson): the GIoU op sequence below is
// empirically pinned — a single-rcp refactor flipped a dataset overlap
// near-tie vs numpy twice (absmax 66 both times). DO NOT refactor it.
// NOTE (r14 lesson): 512-thread/2-gt variants spill (WRITE_SIZE 24 MB).
// NOTE (r16 lesson): single-wave register-resident phase 2 FAILED
// (occupancy 55->24%, VGPR 36->84 + spill).
// NOTE (r18/r19 lessons): reg-cached merges and wave-local top-13 both
// REGRESSED; added instructions cost ~proportionally.
// NOTE (r20 lesson): instruction cuts AND butterfly-latency cuts are
// NEUTRAL -> floor = per-gt L2 panel re-read + barriers + s_key stream.
// NOTE (r21 lesson, RACE): interleaving two gts' rounds between SHARED
// barriers FAILED (absmax 300): a non-owner wave for gt0 races ahead and
// WRITES s_w1[wave] before the gt0-owner wave has READ s_w1 -> round-k
// readers see round-k+1 state. FIX: one barrier BETWEEN the gt0 and gt1
// sections. Every s_w* write is now separated from its next read by a
// full barrier — strictly more race-free than the validated r0 scheme.
__device__ __forceinline__ float frcp(float x) { return __builtin_amdgcn_rcpf(x); }
__device__ __forceinline__ float fexp(float x) {  // e^x via v_exp_f32
    return __builtin_amdgcn_exp2f(x * 1.44269504088896341f);
}

// -GIoU from pred xyxy (p.x=x1,p.y=y1,p.z=x2,p.w=y2) with pred area passed in.
// Two-rcp form, op sequence identical since round 7 (known-good, dataset-
// validated vs numpy).
__device__ __forceinline__ float neg_giou_pa(float4 p, float pa, float gx1, float gy1,
                                             float gx2, float gy2, float garea) {
    float whx = fmaxf(fminf(p.z, gx2) - fmaxf(p.x, gx1), 0.0f);
    float why = fmaxf(fminf(p.w, gy2) - fmaxf(p.y, gy1), 0.0f);
    float inter = whx * why;
    float uni = pa + garea - inter;
    float iou = inter * frcp(uni);
    float wex = fmaxf(p.z, gx2) - fminf(p.x, gx1);
    float wey = fmaxf(p.w, gy2) - fminf(p.y, gy1);
    float area_e = wex * wey;                    // valid boxes -> > 0
    return (area_e - uni) * frcp(area_e) - iou;  // == -(iou - (area_e-uni)/area_e)
}

// cxcywh -> xyxy
__device__ __forceinline__ float4 to_xyxy(float4 pb) {
    return make_float4(pb.x - 0.5f * pb.z, pb.y - 0.5f * pb.w,
                       pb.x + 0.5f * pb.z, pb.y + 0.5f * pb.w);
}

__device__ __forceinline__ float sigmoid_fast(float x) {
    return frcp(1.0f + fexp(-x));
}

__device__ __forceinline__ float pow6(float x) {   // square-and-multiply order
    float x2 = x * x;
    float x4 = x2 * x2;
    return x2 * x4;
}

// strictly monotone float -> uint (used only for the overlap in the scatter key)
__device__ __forceinline__ unsigned ord_float(float f) {
    unsigned u = __float_as_uint(f);
    return u ^ ((unsigned)(((int)u) >> 31) | 0x80000000u);
}

// pack (alignment, pred index): u64 '>' == (alignment desc, n asc).
// alignment >= +0 always (v = s*x^6, s>0, x^6 >= +0, never -0/NaN);
// high word 0 == "not positive" == is_pos false. 0ULL is a safe "empty"
// sentinel (real keys have low word ~n != 0).
__device__ __forceinline__ u64 pack_key(float v, int n) {
    return ((u64)__float_as_uint(v) << 32) | (u64)(~(unsigned)n);
}

// Wave max of the 64 lanes' b1 keys, float-domain fast path (validated r5).
// f32 '>' matches the u64 value-word order for these values; unique max
// holder -> its b1 IS the wave max key; exact bit-tie -> u64 butterfly.
__device__ __forceinline__ u64 wave_max_key(u64 b1) {
    float fv = __uint_as_float((unsigned)(b1 >> 32));
    float mv = fv;
    #pragma unroll
    for (int m = 1; m < 64; m <<= 1)
        mv = fmaxf(mv, __shfl_xor(mv, m, 64));
    u64 tied = __ballot(fv == mv);
    if ((tied & (tied - 1)) == 0ULL) {           // exactly one max holder
        int src = __ffsll((unsigned long long)tied) - 1;
        return __shfl(b1, src, 64);              // uniform src -> readlane x2
    }
    u64 t = b1;                                  // exact-tie fallback (rare)
    #pragma unroll
    for (int m = 1; m < 64; m <<= 1) {
        u64 o = __shfl_xor(t, m, 64);
        if (o > t) t = o;
    }
    return t;
}

// COLD path: rebuild a thread's top-2 for one gt by RECOMPUTING its preds
// from global (identical loads + identical op sequence -> bit-identical
// values). mask bit (j*4+i) set == pred consumed == excluded (exactly the
// old s_key[n]=0 semantics: zeroed keys could never win — high word 0).
template <bool PRE>
__device__ __attribute__((noinline)) void rescan_gt(
        const float4* __restrict__ srow4, const float* __restrict__ lg,
        const float4* __restrict__ par4, const float4* __restrict__ pxr,
        const float4* __restrict__ pbb,
        float gx1, float gy1, float gx2, float gy2, float garea,
        int tid, unsigned mask, u64& r1, u64& r2) {
    r1 = 0ULL; r2 = 0ULL;
    for (int j = 0; j < 4; ++j) {
        int grp = tid + j * 256;
        if (grp >= NGROUP) continue;
        int n0 = grp * 4;
        float s0, s1, s2, s3;
        float4 p0, p1, p2, p3;
        float a0, a1, a2, a3;
        if (PRE) {
            float4 s4 = srow4[grp];
            s0 = s4.x; s1 = s4.y; s2 = s4.z; s3 = s4.w;
            float4 a4 = par4[grp];
            a0 = a4.x; a1 = a4.y; a2 = a4.z; a3 = a4.w;
            p0 = pxr[n0]; p1 = pxr[n0 + 1]; p2 = pxr[n0 + 2]; p3 = pxr[n0 + 3];
        } else {
            s0 = sigmoid_fast(lg[(size_t)(n0 + 0) * NCLS]);
            s1 = sigmoid_fast(lg[(size_t)(n0 + 1) * NCLS]);
            s2 = sigmoid_fast(lg[(size_t)(n0 + 2) * NCLS]);
            s3 = sigmoid_fast(lg[(size_t)(n0 + 3) * NCLS]);
            p0 = to_xyxy(pbb[n0]);     p1 = to_xyxy(pbb[n0 + 1]);
            p2 = to_xyxy(pbb[n0 + 2]); p3 = to_xyxy(pbb[n0 + 3]);
            a0 = (p0.z - p0.x) * (p0.w - p0.y);
            a1 = (p1.z - p1.x) * (p1.w - p1.y);
            a2 = (p2.z - p2.x) * (p2.w - p2.y);
            a3 = (p3.z - p3.x) * (p3.w - p3.y);
        }
        float v0 = s0 * pow6(neg_giou_pa(p0, a0, gx1, gy1, gx2, gy2, garea));
        float v1 = s1 * pow6(neg_giou_pa(p1, a1, gx1, gy1, gx2, gy2, garea));
        float v2 = s2 * pow6(neg_giou_pa(p2, a2, gx1, gy1, gx2, gy2, garea));
        float v3 = s3 * pow6(neg_giou_pa(p3, a3, gx1, gy1, gx2, gy2, garea));
        unsigned mj = mask >> (j * 4);
        if (!(mj & 1u)) { u64 c = pack_key(v0, n0);
            if (c > r1) { r2 = r1; r1 = c; } else if (c > r2) r2 = c; }
        if (!(mj & 2u)) { u64 c = pack_key(v1, n0 + 1);
            if (c > r1) { r2 = r1; r1 = c; } else if (c > r2) r2 = c; }
        if (!(mj & 4u)) { u64 c = pack_key(v2, n0 + 2);
            if (c > r1) { r2 = r1; r1 = c; } else if (c > r2) r2 = c; }
        if (!(mj & 8u)) { u64 c = pack_key(v3, n0 + 3);
            if (c > r1) { r2 = r1; r1 = c; } else if (c > r2) r2 = c; }
    }
}

__global__ void init_keys(u64* keys, int n) {   // fallback path only
    int i = blockIdx.x * blockDim.x + threadIdx.x;
    if (i < n) keys[i] = 0ULL;
}

// Precompute st[b][c][n] = sigmoid(logits[b][n][c]) via LDS tile transpose,
// plus pred xyxy and pred area per (b,n). Also zeroes the keys array.
// 32-pred chunks (4000 = 125*32 exactly -> no bounds checks), 2000 blocks.
__global__ __launch_bounds__(256) void sig_transpose(const float* __restrict__ logits,
                                                     const float4* __restrict__ pboxes,
                                                     float* __restrict__ st,
                                                     float4* __restrict__ pxyxy,
                                                     float* __restrict__ parea,
                                                     u64* __restrict__ keys,
                                                     int total_keys) {
    const int tid = threadIdx.x;
    const int gid = blockIdx.x * 256 + tid;
    if (gid < total_keys) keys[gid] = 0ULL;

    const int b = blockIdx.x / NCHUNK;
    const int n0 = (blockIdx.x % NCHUNK) * 32;

    if (tid < 32) {
        int n = n0 + tid;
        float4 x = to_xyxy(pboxes[(size_t)b * NPRED + n]);
        pxyxy[(size_t)b * NPRED + n] = x;
        // same ops as in-kernel pa = (p.z-p.x)*(p.w-p.y): identical bits
        parea[(size_t)b * NPRED + n] = (x.z - x.x) * (x.w - x.y);
    }

    __shared__ float tile[NCLS][32 + 1];

    // read: 32 preds x 80 classes = 640 float4 (4 consecutive classes each)
    const float4* src = (const float4*)(logits + ((size_t)b * NPRED + n0) * NCLS);
    #pragma unroll
    for (int it = 0; it < 3; ++it) {
        int i4 = tid + it * 256;            // < 640
        if (i4 < 640) {
            int p = i4 / 20;                // 20 float4 per pred (80 classes)
            int c = (i4 - p * 20) * 4;
            float4 v = src[i4];
            tile[c + 0][p] = sigmoid_fast(v.x);
            tile[c + 1][p] = sigmoid_fast(v.y);
            tile[c + 2][p] = sigmoid_fast(v.z);
            tile[c + 3][p] = sigmoid_fast(v.w);
        }
    }
    __syncthreads();
    // write: per class, 32 floats = 8 float4 (8 lanes share a class row)
    float* dstbase = st + (size_t)b * NCLS * NPRED + n0;
    #pragma unroll
    for (int it = 0; it < 3; ++it) {
        int w4 = tid + it * 256;            // < 640
        if (w4 < 640) {
            int c = w4 >> 3, r4 = (w4 & 7) * 4;
            float4 v = make_float4(tile[c][r4], tile[c][r4 + 1],
                                   tile[c][r4 + 2], tile[c][r4 + 3]);
            *(float4*)(dstbase + (size_t)c * NPRED + r4) = v;
        }
    }
}

// One block (256 thr = 4 waves) per (b, gt-PAIR): g0 = 2*gp, g1 = g0+1.
// Thread owns pred groups grp = tid + 256j (j<4) — the SAME preds for both
// gts, so the pred panel (pxyxy/parea + two st rows) is loaded ONCE per
// block and evaluated against both gts (L2 bytes/gt -42%).
// Phase 1: eval -> per-thread FLOAT-domain top-2 per gt (r5-validated);
//          pack to u64 at loop end. NO s_key: consumed preds tracked in a
//          16-bit register mask; the rare both-consumed case recomputes
//          from global, bit-stable (rescan_gt).
// Phase 2: up to 13 rounds. Each round: barrier -> gt0 round (merge s_w0,
//          pop, owner-wave re-reduce, write s_w0) -> barrier -> gt1 round.
//          Every s_w* write is separated from its next read by a full
//          barrier (r21 race fix). 26 barriers/block serving 2 gts ==
//          13 effective barriers per gt (half of the r0 scheme).
// Phase 3: winners scatter atomicMax keys (gt0 on wave-0 lanes, gt1 on
//          wave 1): ord(overlap)[63:32] | (511-g)[31:23] | metric[22:7].
template <bool PRE>
__global__ __launch_bounds__(256) void topk_scatter(const float* __restrict__ logits,
                                                    const float* __restrict__ st,
                                                    const float4* __restrict__ pboxes,
                                                    const float4* __restrict__ pxyxy,
                                                    const float* __restrict__ parea,
                                                    const float4* __restrict__ gboxes,
                                                    const int* __restrict__ glabels,
                                                    u64* __restrict__ keys) {
    const int blk = blockIdx.x;
    const int b = blk / NGTH;
    const int gp = blk - b * NGTH;
    const int g0 = gp * 2, g1 = g0 + 1;
    const int tid = threadIdx.x;
    const int wave = tid >> 6;
    const int lane = tid & 63;

    __shared__ u64 s_w0[4], s_w1[4];             // per-wave maxima, per gt
    __shared__ u64 s_win0[TOPKK], s_win1[TOPKK];

    float4 gb0 = gboxes[b * NGT + g0];
    float4 gb1 = gboxes[b * NGT + g1];
    const int lab0 = glabels[b * NGT + g0];
    const int lab1 = glabels[b * NGT + g1];
    const float gx10 = gb0.x - 0.5f * gb0.z, gy10 = gb0.y - 0.5f * gb0.w;
    const float gx20 = gb0.x + 0.5f * gb0.z, gy20 = gb0.y + 0.5f * gb0.w;
    const float garea0 = (gx20 - gx10) * (gy20 - gy10);
    const float gx11 = gb1.x - 0.5f * gb1.z, gy11 = gb1.y - 0.5f * gb1.w;
    const float gx21 = gb1.x + 0.5f * gb1.z, gy21 = gb1.y + 0.5f * gb1.w;
    const float garea1 = (gx21 - gx11) * (gy21 - gy11);

    const float* lg0 = logits + (size_t)b * NPRED * NCLS + lab0;
    const float* lg1 = logits + (size_t)b * NPRED * NCLS + lab1;
    const float4* srow4_0 = (const float4*)(st + ((size_t)b * NCLS + lab0) * NPRED);
    const float4* srow4_1 = (const float4*)(st + ((size_t)b * NCLS + lab1) * NPRED);
    const float4* par4 = (const float4*)(parea + (size_t)b * NPRED);
    const float4* pbb = pboxes + (size_t)b * NPRED;
    const float4* pxr = pxyxy + (size_t)b * NPRED;

    // --- phase 1: shared pred loads, FLOAT-domain top-2 per gt (r5-valid) ---
    float bv10 = -1.0f, bv20 = -1.0f;  int bn10 = 0, bn20 = 0;   // gt0
    float bv11 = -1.0f, bv21 = -1.0f;  int bn11 = 0, bn21 = 0;   // gt1
    #pragma unroll
    for (int j = 0; j < 4; ++j) {
        int grp = tid + j * 256;
        if (grp < NGROUP) {
            int n0 = grp * 4;
            float sa0, sa1, sa2, sa3, sb0, sb1, sb2, sb3;
            float4 p0, p1, p2, p3;
            float a0, a1, a2, a3;
            if (PRE) {
                float4 s4a = srow4_0[grp];
                sa0 = s4a.x; sa1 = s4a.y; sa2 = s4a.z; sa3 = s4a.w;
                float4 s4b = srow4_1[grp];
                sb0 = s4b.x; sb1 = s4b.y; sb2 = s4b.z; sb3 = s4b.w;
                float4 a4 = par4[grp];
                a0 = a4.x; a1 = a4.y; a2 = a4.z; a3 = a4.w;
                p0 = pxr[n0]; p1 = pxr[n0 + 1]; p2 = pxr[n0 + 2]; p3 = pxr[n0 + 3];
            } else {
                sa0 = sigmoid_fast(lg0[(size_t)(n0 + 0) * NCLS]);
                sa1 = sigmoid_fast(lg0[(size_t)(n0 + 1) * NCLS]);
                sa2 = sigmoid_fast(lg0[(size_t)(n0 + 2) * NCLS]);
                sa3 = sigmoid_fast(lg0[(size_t)(n0 + 3) * NCLS]);
                sb0 = sigmoid_fast(lg1[(size_t)(n0 + 0) * NCLS]);
                sb1 = sigmoid_fast(lg1[(size_t)(n0 + 1) * NCLS]);
                sb2 = sigmoid_fast(lg1[(size_t)(n0 + 2) * NCLS]);
                sb3 = sigmoid_fast(lg1[(size_t)(n0 + 3) * NCLS]);
                p0 = to_xyxy(pbb[n0]);     p1 = to_xyxy(pbb[n0 + 1]);
                p2 = to_xyxy(pbb[n0 + 2]); p3 = to_xyxy(pbb[n0 + 3]);
                a0 = (p0.z - p0.x) * (p0.w - p0.y);
                a1 = (p1.z - p1.x) * (p1.w - p1.y);
                a2 = (p2.z - p2.x) * (p2.w - p2.y);
                a3 = (p3.z - p3.x) * (p3.w - p3.y);
            }
            // gt0
            {
                float v0 = sa0 * pow6(neg_giou_pa(p0, a0, gx10, gy10, gx20, gy20, garea0));
                float v1 = sa1 * pow6(neg_giou_pa(p1, a1, gx10, gy10, gx20, gy20, garea0));
                float v2 = sa2 * pow6(neg_giou_pa(p2, a2, gx10, gy10, gx20, gy20, garea0));
                float v3 = sa3 * pow6(neg_giou_pa(p3, a3, gx10, gy10, gx20, gy20, garea0));
                if (v0 > bv10) { bv20 = bv10; bn20 = bn10; bv10 = v0; bn10 = n0; }
                else if (v0 > bv20) { bv20 = v0; bn20 = n0; }
                if (v1 > bv10) { bv20 = bv10; bn20 = bn10; bv10 = v1; bn10 = n0 + 1; }
                else if (v1 > bv20) { bv20 = v1; bn20 = n0 + 1; }
                if (v2 > bv10) { bv20 = bv10; bn20 = bn10; bv10 = v2; bn10 = n0 + 2; }
                else if (v2 > bv20) { bv20 = v2; bn20 = n0 + 2; }
                if (v3 > bv10) { bv20 = bv10; bn20 = bn10; bv10 = v3; bn10 = n0 + 3; }
                else if (v3 > bv20) { bv20 = v3; bn20 = n0 + 3; }
            }
            // gt1
            {
                float v0 = sb0 * pow6(neg_giou_pa(p0, a0, gx11, gy11, gx21, gy21, garea1));
                float v1 = sb1 * pow6(neg_giou_pa(p1, a1, gx11, gy11, gx21, gy21, garea1));
                float v2 = sb2 * pow6(neg_giou_pa(p2, a2, gx11, gy11, gx21, gy21, garea1));
                float v3 = sb3 * pow6(neg_giou_pa(p3, a3, gx11, gy11, gx21, gy21, garea1));
                if (v0 > bv11) { bv21 = bv11; bn21 = bn11; bv11 = v0; bn11 = n0; }
                else if (v0 > bv21) { bv21 = v0; bn21 = n0; }
                if (v1 > bv11) { bv21 = bv11; bn21 = bn11; bv11 = v1; bn11 = n0 + 1; }
                else if (v1 > bv21) { bv21 = v1; bn21 = n0 + 1; }
                if (v2 > bv11) { bv21 = bv11; bn21 = bn11; bv11 = v2; bn11 = n0 + 2; }
                else if (v2 > bv21) { bv21 = v2; bn21 = n0 + 2; }
                if (v3 > bv11) { bv21 = bv11; bn21 = bn11; bv11 = v3; bn11 = n0 + 3; }
                else if (v3 > bv21) { bv21 = v3; bn21 = n0 + 3; }
            }
        }
    }
    u64 b1g0 = pack_key(bv10, bn10), b2g0 = pack_key(bv20, bn20);
    u64 b1g1 = pack_key(bv11, bn11), b2g1 = pack_key(bv21, bn21);
    unsigned mask0 = 0u, mask1 = 0u;

    // initial per-wave maxima (both gts); first reads are after a barrier
    {
        u64 m = wave_max_key(b1g0);
        if (lane == 0) s_w0[wave] = m;
        m = wave_max_key(b1g1);
        if (lane == 0) s_w1[wave] = m;
    }

    // --- phase 2: per round: barrier -> gt0 -> barrier -> gt1 ---
    int nwin0 = 0, nwin1 = 0;
    bool done0 = false, done1 = false;
    for (int k = 0; k < TOPKK; ++k) {
        __syncthreads();                      // s_w0 stable (written pre-loop
        // gt0 round                          //  or before round k-1's 2nd bar)
        if (!done0) {
            u64 t = s_w0[0];
            u64 c;
            c = s_w0[1]; if (c > t) t = c;
            c = s_w0[2]; if (c > t) t = c;
            c = s_w0[3]; if (c > t) t = c;
            if ((unsigned)(t >> 32) == 0u) done0 = true;
            else {
                if (tid == 0) s_win0[k] = t;
                nwin0 = k + 1;
                if (k < TOPKK - 1) {
                    int n1 = (int)(~(unsigned)t);
                    int ownerTid = (n1 >> 2) & 255;
                    if (tid == ownerTid) {
                        mask0 |= 1u << (((n1 >> 10) << 2) | (n1 & 3));
                        if (b2g0 != 0ULL) { b1g0 = b2g0; b2g0 = 0ULL; }
                        else rescan_gt<PRE>(srow4_0, lg0, par4, pxr, pbb,
                                            gx10, gy10, gx20, gy20, garea0,
                                            tid, mask0, b1g0, b2g0);
                    }
                    if ((ownerTid >> 6) == wave) {
                        u64 m = wave_max_key(b1g0);
                        if (lane == 0) s_w0[wave] = m;
                    }
                }
            }
        }
        __syncthreads();                      // fences s_w0 write; s_w1 stable
        // gt1 round
        if (!done1) {
            u64 t = s_w1[0];
            u64 c;
            c = s_w1[1]; if (c > t) t = c;
            c = s_w1[2]; if (c > t) t = c;
            c = s_w1[3]; if (c > t) t = c;
            if ((unsigned)(t >> 32) == 0u) done1 = true;
            else {
                if (tid == 0) s_win1[k] = t;
                nwin1 = k + 1;
                if (k < TOPKK - 1) {
                    int n1 = (int)(~(unsigned)t);
                    int ownerTid = (n1 >> 2) & 255;
                    if (tid == ownerTid) {
                        mask1 |= 1u << (((n1 >> 10) << 2) | (n1 & 3));
                        if (b2g1 != 0ULL) { b1g1 = b2g1; b2g1 = 0ULL; }
                        else rescan_gt<PRE>(srow4_1, lg1, par4, pxr, pbb,
                                            gx11, gy11, gx21, gy21, garea1,
                                            tid, mask1, b1g1, b2g1);
                    }
                    if ((ownerTid >> 6) == wave) {
                        u64 m = wave_max_key(b1g1);
                        if (lane == 0) s_w1[wave] = m;
                    }
                }
            }
        }
        if (done0 && done1) break;            // block-uniform
    }
    __syncthreads();                          // publish s_win0/s_win1

    // --- phase 3: parallel scatter (gt0 on wave 0 lanes, gt1 on wave 1) ---
    if (tid < nwin0) {
        u64 t = s_win0[tid];
        int wi = (int)(~(unsigned)t);
        float4 p;
        if (PRE) p = pxr[wi];
        else     p = to_xyxy(pbb[wi]);
        float pa = (p.z - p.x) * (p.w - p.y);   // same ops -> same bits as eval
        float o = neg_giou_pa(p, pa, gx10, gy10, gx20, gy20, garea0);
        unsigned mbits = (unsigned)(t >> 32) >> 16;
        u64 key = ((u64)ord_float(o) << 32)
                | ((u64)(511u - (unsigned)g0) << 23)
                | ((u64)mbits << 7);
        atomicMax(&keys[(size_t)b * NPRED + wi], key);
    } else if (tid >= 64 && tid < 64 + nwin1) {
        u64 t = s_win1[tid - 64];
        int wi = (int)(~(unsigned)t);
        float4 p;
        if (PRE) p = pxr[wi];
        else     p = to_xyxy(pbb[wi]);
        float pa = (p.z - p.x) * (p.w - p.y);
        float o = neg_giou_pa(p, pa, gx11, gy11, gx21, gy21, garea1);
        unsigned mbits = (unsigned)(t >> 32) >> 16;
        u64 key = ((u64)ord_float(o) << 32)
                | ((u64)(511u - (unsigned)g1) << 23)
                | ((u64)mbits << 7);
        atomicMax(&keys[(size_t)b * NPRED + wi], key);
    }
}

// Per (b,n): pure decode of the packed key -> 3 float32 planes.
__global__ void finalize(const int* __restrict__ glabels,
                         const u64* __restrict__ keys,
                         float* __restrict__ out, int total) {
    int i = blockIdx.x * blockDim.x + threadIdx.x;
    if (i >= total) return;
    int b = i / NPRED;
    u64 key = keys[i];
    float o0 = 0.0f, o1 = -1.0f, o2 = 0.0f;
    if (key != 0ULL) {
        int g = 511 - (int)((key >> 23) & 0x1FF);
        o0 = (float)(g + 1);
        o1 = (float)glabels[b * NGT + g];
        o2 = __uint_as_float(((unsigned)(key >> 7) & 0xFFFFu) << 16);
    }
    out[i] = o0;
    out[(size_t)total + i] = o1;
    out[(size_t)2 * total + i] = o2;
}

extern "C" void kernel_launch(void* const* d_in, const int* in_sizes, int n_in,
                              void* d_out, int out_size, void* d_ws, size_t ws_size,
                              hipStream_t stream) {
    const float* logits  = (const float*)d_in[0];
    const float4* pboxes = (const float4*)d_in[1];
    const float4* gboxes = (const float4*)d_in[2];
    const int* glabels   = (const int*)d_in[3];

    const int bs = in_sizes[3] / NGT;          // 16
    const int total = bs * NPRED;              // 64000
    char* ws = (char*)d_ws;
    u64* keys   = (u64*)ws;                    ws += (size_t)total * 8;
    float* st   = (float*)ws;                  ws += (size_t)bs * NCLS * NPRED * 4;
    float4* pxy = (float4*)ws;                 ws += (size_t)total * 16;
    float* par  = (float*)ws;                  ws += (size_t)total * 4;
    float* out = (float*)d_out;

    const size_t need = (size_t)(ws - (char*)d_ws);
    if (ws_size >= need) {
        sig_transpose<<<bs * NCHUNK, 256, 0, stream>>>(logits, pboxes, st, pxy,
                                                       par, keys, total);
        topk_scatter<true><<<bs * NGTH, 256, 0, stream>>>(logits, st, pboxes, pxy,
                                                          par, gboxes, glabels, keys);
    } else {
        init_keys<<<(total + 255) / 256, 256, 0, stream>>>(keys, total);
        topk_scatter<false><<<bs * NGTH, 256, 0, stream>>>(logits, st, pboxes, pxy,
                                                           par, gboxes, glabels, keys);
    }
    finalize<<<(total + 255) / 256, 256, 0, stream>>>(glabels, keys, out, total);
}

// Round 8
// 123.484 us; speedup vs baseline: 1.3337x; 1.3337x over previous
//
#include <hip/hip_runtime.h>

#define NPRED  4000
#define NGROUP 1000   // NPRED / 4
#define NGT    300
#define NCLS   80
#define TOPKK  13
#define NCHUNK 125    // NPRED / 32 (exact)

typedef unsigned long long u64;

// Fast-math ops: ordering-safe — pass threshold is 6.0; only discrete
// selections matter. NOTE (r9/r13 lesson): the GIoU op sequence below is
// empirically pinned — a single-rcp refactor flipped a dataset overlap
// near-tie vs numpy twice (absmax 66 both times). DO NOT refactor it.
// The pred area 'pa' is hoisted to sig_transpose, computed with EXACTLY
// the same ops on the same xyxy values -> identical bits fed in here.
// ===== SESSION LEDGER (do not re-walk these dead ends) =====
// r14: 512-thread/2-gt variants spill (WRITE_SIZE 24 MB).
// r16: single-wave register-resident phase 2 FAILED (LDS held to block
//      exit -> occupancy 55->24%, VALUBusy 65->15%, VGPR 36->84 + spill).
// r17: -48 VALU/thread trim invisible (~2% of issue budget).
// r18: per-round reg-cached s_wave merge REGRESSED 51->58 µs (register
//      dep-chains + uniform branches lose to broadcast LDS reads).
// r19: wave-local top-13 + merge REGRESSED 51->69 µs (4x butterfly work;
//      time tracks instruction count; removing barriers did NOT pay).
// r20: float-domain compare cuts NEUTRAL (VALUBusy 65->61, time const) ->
//      plateau is stall-slack-absorbing, not issue-throughput-tight.
// r21: 2-gt rounds interleaved between SHARED barriers -> RACE (absmax
//      300): non-owner wave writes s_w1 before gt0-owner reads it.
// r22: 2-gt with barrier-separated sections + noinline recompute-rescan ->
//      call-ABI + dual accumulators SPILL (WRITE_SIZE 26.8 MB, topk 92 µs).
// CONCLUSION: this 4-wave barrier-pumped skeleton at 256 thr / 1 gt per
// block is the measured local optimum (topk ~51 µs, total ~122.7 µs).
__device__ __forceinline__ float frcp(float x) { return __builtin_amdgcn_rcpf(x); }
__device__ __forceinline__ float fexp(float x) {  // e^x via v_exp_f32
    return __builtin_amdgcn_exp2f(x * 1.44269504088896341f);
}

// -GIoU from pred xyxy (p.x=x1,p.y=y1,p.z=x2,p.w=y2) with pred area passed in.
// Two-rcp form, op sequence identical since round 7 (known-good, dataset-
// validated vs numpy).
__device__ __forceinline__ float neg_giou_pa(float4 p, float pa, float gx1, float gy1,
                                             float gx2, float gy2, float garea) {
    float whx = fmaxf(fminf(p.z, gx2) - fmaxf(p.x, gx1), 0.0f);
    float why = fmaxf(fminf(p.w, gy2) - fmaxf(p.y, gy1), 0.0f);
    float inter = whx * why;
    float uni = pa + garea - inter;
    float iou = inter * frcp(uni);
    float wex = fmaxf(p.z, gx2) - fminf(p.x, gx1);
    float wey = fmaxf(p.w, gy2) - fminf(p.y, gy1);
    float area_e = wex * wey;                    // valid boxes -> > 0
    return (area_e - uni) * frcp(area_e) - iou;  // == -(iou - (area_e-uni)/area_e)
}

// cxcywh -> xyxy
__device__ __forceinline__ float4 to_xyxy(float4 pb) {
    return make_float4(pb.x - 0.5f * pb.z, pb.y - 0.5f * pb.w,
                       pb.x + 0.5f * pb.z, pb.y + 0.5f * pb.w);
}

__device__ __forceinline__ float sigmoid_fast(float x) {
    return frcp(1.0f + fexp(-x));
}

__device__ __forceinline__ float pow6(float x) {   // square-and-multiply order
    float x2 = x * x;
    float x4 = x2 * x2;
    return x2 * x4;
}

// strictly monotone float -> uint (used only for the overlap in the scatter key)
__device__ __forceinline__ unsigned ord_float(float f) {
    unsigned u = __float_as_uint(f);
    return u ^ ((unsigned)(((int)u) >> 31) | 0x80000000u);
}

// pack (alignment, pred index): u64 '>' == (alignment desc, n asc).
// alignment >= +0 always; high word 0 == "not positive" == is_pos false.
__device__ __forceinline__ u64 pack_key(float v, int n) {
    return ((u64)__float_as_uint(v) << 32) | (u64)(~(unsigned)n);
}

__global__ void init_keys(u64* keys, int n) {   // fallback path only
    int i = blockIdx.x * blockDim.x + threadIdx.x;
    if (i < n) keys[i] = 0ULL;
}

// Precompute st[b][c][n] = sigmoid(logits[b][n][c]) via LDS tile transpose,
// plus pred xyxy and pred area per (b,n). Also zeroes the keys array.
// 32-pred chunks (4000 = 125*32 exactly -> no bounds checks), 2000 blocks.
__global__ __launch_bounds__(256) void sig_transpose(const float* __restrict__ logits,
                                                     const float4* __restrict__ pboxes,
                                                     float* __restrict__ st,
                                                     float4* __restrict__ pxyxy,
                                                     float* __restrict__ parea,
                                                     u64* __restrict__ keys,
                                                     int total_keys) {
    const int tid = threadIdx.x;
    const int gid = blockIdx.x * 256 + tid;
    if (gid < total_keys) keys[gid] = 0ULL;

    const int b = blockIdx.x / NCHUNK;
    const int n0 = (blockIdx.x % NCHUNK) * 32;

    if (tid < 32) {
        int n = n0 + tid;
        float4 x = to_xyxy(pboxes[(size_t)b * NPRED + n]);
        pxyxy[(size_t)b * NPRED + n] = x;
        // same ops as in-kernel pa = (p.z-p.x)*(p.w-p.y): identical bits
        parea[(size_t)b * NPRED + n] = (x.z - x.x) * (x.w - x.y);
    }

    __shared__ float tile[NCLS][32 + 1];

    // read: 32 preds x 80 classes = 640 float4 (4 consecutive classes each)
    const float4* src = (const float4*)(logits + ((size_t)b * NPRED + n0) * NCLS);
    #pragma unroll
    for (int it = 0; it < 3; ++it) {
        int i4 = tid + it * 256;            // < 640
        if (i4 < 640) {
            int p = i4 / 20;                // 20 float4 per pred (80 classes)
            int c = (i4 - p * 20) * 4;
            float4 v = src[i4];
            tile[c + 0][p] = sigmoid_fast(v.x);
            tile[c + 1][p] = sigmoid_fast(v.y);
            tile[c + 2][p] = sigmoid_fast(v.z);
            tile[c + 3][p] = sigmoid_fast(v.w);
        }
    }
    __syncthreads();
    // write: per class, 32 floats = 8 float4 (8 lanes share a class row)
    float* dstbase = st + (size_t)b * NCLS * NPRED + n0;
    #pragma unroll
    for (int it = 0; it < 3; ++it) {
        int w4 = tid + it * 256;            // < 640
        if (w4 < 640) {
            int c = w4 >> 3, r4 = (w4 & 7) * 4;
            float4 v = make_float4(tile[c][r4], tile[c][r4 + 1],
                                   tile[c][r4 + 2], tile[c][r4 + 3]);
            *(float4*)(dstbase + (size_t)c * NPRED + r4) = v;
        }
    }
}

// One block (256 thr = 4 waves) per (b, g). Thread owns pred groups
// grp = tid + 256j (j<4), preds n = 4*grp .. 4*grp+3.
// Phase 1: eval all preds -> LDS float alignments + per-thread top-2 packed
//          u64 keys in regs; then each wave caches its max in s_wave[wave].
// Phase 2: 13 rounds, 1 barrier each. All threads do a uniform 4-entry LDS
//          merge (no shuffles) -> block winner. Only the OWNER'S WAVE re-runs
//          the 12-op butterfly to refresh its cached max; owner thread pops
//          (promote cached b2, else rescan STORED LDS floats — bit-stable).
//          u64 order == (alignment desc, n asc) == top_k stability.
// Phase 3: winners scatter atomicMax keys packing the full result:
//          ord(overlap)[63:32] | (511-g)[31:23] | metric_top16[22:7].
template <bool PRE>
__global__ __launch_bounds__(256) void topk_scatter(const float* __restrict__ logits,
                                                    const float* __restrict__ st,
                                                    const float4* __restrict__ pboxes,
                                                    const float4* __restrict__ pxyxy,
                                                    const float* __restrict__ parea,
                                                    const float4* __restrict__ gboxes,
                                                    const int* __restrict__ glabels,
                                                    u64* __restrict__ keys) {
    const int blk = blockIdx.x;
    const int b = blk / NGT;
    const int g = blk - b * NGT;
    const int tid = threadIdx.x;
    const int wave = tid >> 6;
    const int lane = tid & 63;

    __shared__ __align__(16) float s_key[NPRED];   // 16 KB raw float alignment
    __shared__ u64 s_wave[4];                      // cached per-wave max
    __shared__ u64 s_win[TOPKK];

    float4 gb = gboxes[b * NGT + g];
    const int lab = glabels[b * NGT + g];
    const float gx1 = gb.x - 0.5f * gb.z;
    const float gy1 = gb.y - 0.5f * gb.w;
    const float gx2 = gb.x + 0.5f * gb.z;
    const float gy2 = gb.y + 0.5f * gb.w;
    const float garea = (gx2 - gx1) * (gy2 - gy1);

    const float* lg = logits + (size_t)b * NPRED * NCLS + lab;
    const float* srow = st + ((size_t)b * NCLS + lab) * NPRED;
    const float4* srow4 = (const float4*)srow;
    const float4* par4 = (const float4*)(parea + (size_t)b * NPRED);
    const float4* pbb = pboxes + (size_t)b * NPRED;
    const float4* pxr = pxyxy + (size_t)b * NPRED;

    // --- phase 1: eval owned preds, LDS store + register top-2 (packed u64) ---
    u64 b1 = 0ULL, b2 = 0ULL;
    #pragma unroll
    for (int j = 0; j < 4; ++j) {
        int grp = tid + j * 256;
        if (grp < NGROUP) {
            int n0 = grp * 4;
            float s0, s1, s2, s3;
            float4 p0, p1, p2, p3;
            float a0, a1, a2, a3;
            if (PRE) {
                float4 s4 = srow4[grp];
                s0 = s4.x; s1 = s4.y; s2 = s4.z; s3 = s4.w;
                float4 a4 = par4[grp];
                a0 = a4.x; a1 = a4.y; a2 = a4.z; a3 = a4.w;
                p0 = pxr[n0]; p1 = pxr[n0 + 1]; p2 = pxr[n0 + 2]; p3 = pxr[n0 + 3];
            } else {
                s0 = sigmoid_fast(lg[(size_t)(n0 + 0) * NCLS]);
                s1 = sigmoid_fast(lg[(size_t)(n0 + 1) * NCLS]);
                s2 = sigmoid_fast(lg[(size_t)(n0 + 2) * NCLS]);
                s3 = sigmoid_fast(lg[(size_t)(n0 + 3) * NCLS]);
                p0 = to_xyxy(pbb[n0]);     p1 = to_xyxy(pbb[n0 + 1]);
                p2 = to_xyxy(pbb[n0 + 2]); p3 = to_xyxy(pbb[n0 + 3]);
                a0 = (p0.z - p0.x) * (p0.w - p0.y);
                a1 = (p1.z - p1.x) * (p1.w - p1.y);
                a2 = (p2.z - p2.x) * (p2.w - p2.y);
                a3 = (p3.z - p3.x) * (p3.w - p3.y);
            }
            float v0 = s0 * pow6(neg_giou_pa(p0, a0, gx1, gy1, gx2, gy2, garea));
            float v1 = s1 * pow6(neg_giou_pa(p1, a1, gx1, gy1, gx2, gy2, garea));
            float v2 = s2 * pow6(neg_giou_pa(p2, a2, gx1, gy1, gx2, gy2, garea));
            float v3 = s3 * pow6(neg_giou_pa(p3, a3, gx1, gy1, gx2, gy2, garea));
            *(float4*)&s_key[n0] = make_float4(v0, v1, v2, v3);
            u64 k0 = pack_key(v0, n0);
            u64 k1 = pack_key(v1, n0 + 1);
            u64 k2 = pack_key(v2, n0 + 2);
            u64 k3 = pack_key(v3, n0 + 3);
            if (k0 > b1) { b2 = b1; b1 = k0; } else if (k0 > b2) b2 = k0;
            if (k1 > b1) { b2 = b1; b1 = k1; } else if (k1 > b2) b2 = k1;
            if (k2 > b1) { b2 = b1; b1 = k2; } else if (k2 > b2) b2 = k2;
            if (k3 > b1) { b2 = b1; b1 = k3; } else if (k3 > b2) b2 = k3;
        }
    }
    // no barrier: every s_key entry is only ever re-read by its writer thread

    // initial per-wave max (12 ds ops per wave, once)
    {
        u64 m1 = b1;
        #pragma unroll
        for (int m = 1; m < 64; m <<= 1) {
            u64 o = __shfl_xor(m1, m, 64);
            if (o > m1) m1 = o;
        }
        if (lane == 0) s_wave[wave] = m1;
    }

    // --- phase 2: 13 rounds, owner-wave-only re-reduce ---
    int nwin = 0;
    for (int k = 0; k < TOPKK; ++k) {
        __syncthreads();                      // s_wave stable for all readers
        u64 t1 = s_wave[0];                   // uniform 4-entry merge, no DS
        u64 c;
        c = s_wave[1]; if (c > t1) t1 = c;
        c = s_wave[2]; if (c > t1) t1 = c;
        c = s_wave[3]; if (c > t1) t1 = c;
        if ((unsigned)(t1 >> 32) == 0u) break;   // is_pos: no positives left
        if (tid == 0) s_win[k] = t1;
        nwin = k + 1;
        int n1 = (int)(~(unsigned)t1);
        int ownerTid = (n1 >> 2) & 255;
        if (tid == ownerTid) {                // pop: winner is this thread's b1
            s_key[n1] = 0.0f;
            if (b2 != 0ULL) { b1 = b2; b2 = 0ULL; }
            else {                            // rescan STORED values (bit-stable)
                b1 = 0ULL;
                #pragma unroll
                for (int jj = 0; jj < 4; ++jj) {
                    int grp = tid + jj * 256;
                    if (grp >= NGROUP) continue;
                    int n0 = grp * 4;
                    float4 q = *(const float4*)&s_key[n0];
                    u64 c0 = pack_key(q.x, n0);
                    u64 c1 = pack_key(q.y, n0 + 1);
                    u64 c2 = pack_key(q.z, n0 + 2);
                    u64 c3 = pack_key(q.w, n0 + 3);
                    if (c0 > b1) { b2 = b1; b1 = c0; } else if (c0 > b2) b2 = c0;
                    if (c1 > b1) { b2 = b1; b1 = c1; } else if (c1 > b2) b2 = c1;
                    if (c2 > b1) { b2 = b1; b1 = c2; } else if (c2 > b2) b2 = c2;
                    if (c3 > b1) { b2 = b1; b1 = c3; } else if (c3 > b2) b2 = c3;
                }
            }
        }
        if ((ownerTid >> 6) == wave) {        // only the owner's wave re-reduces
            u64 m1 = b1;
            #pragma unroll
            for (int m = 1; m < 64; m <<= 1) {
                u64 o = __shfl_xor(m1, m, 64);
                if (o > m1) m1 = o;
            }
            if (lane == 0) s_wave[wave] = m1;
        }
    }
    __syncthreads();                          // publish s_win

    // --- phase 3: parallel scatter with packed payload ---
    if (tid < nwin) {
        u64 t = s_win[tid];
        int wi = (int)(~(unsigned)t);
        float4 p;
        if (PRE) p = pxr[wi];
        else     p = to_xyxy(pbb[wi]);
        float pa = (p.z - p.x) * (p.w - p.y);   // same ops -> same bits as before
        float o = neg_giou_pa(p, pa, gx1, gy1, gx2, gy2, garea);
        unsigned mbits = (unsigned)(t >> 32) >> 16;   // metric > 0, top 16 bits
        u64 key = ((u64)ord_float(o) << 32)
                | ((u64)(511u - (unsigned)g) << 23)
                | ((u64)mbits << 7);
        atomicMax(&keys[(size_t)b * NPRED + wi], key);
    }
}

// Per (b,n): pure decode of the packed key -> 3 float32 planes.
__global__ void finalize(const int* __restrict__ glabels,
                         const u64* __restrict__ keys,
                         float* __restrict__ out, int total) {
    int i = blockIdx.x * blockDim.x + threadIdx.x;
    if (i >= total) return;
    int b = i / NPRED;
    u64 key = keys[i];
    float o0 = 0.0f, o1 = -1.0f, o2 = 0.0f;
    if (key != 0ULL) {
        int g = 511 - (int)((key >> 23) & 0x1FF);
        o0 = (float)(g + 1);
        o1 = (float)glabels[b * NGT + g];
        o2 = __uint_as_float(((unsigned)(key >> 7) & 0xFFFFu) << 16);
    }
    out[i] = o0;
    out[(size_t)total + i] = o1;
    out[(size_t)2 * total + i] = o2;
}

extern "C" void kernel_launch(void* const* d_in, const int* in_sizes, int n_in,
                              void* d_out, int out_size, void* d_ws, size_t ws_size,
                              hipStream_t stream) {
    const float* logits  = (const float*)d_in[0];
    const float4* pboxes = (const float4*)d_in[1];
    const float4* gboxes = (const float4*)d_in[2];
    const int* glabels   = (const int*)d_in[3];

    const int bs = in_sizes[3] / NGT;          // 16
    const int total = bs * NPRED;              // 64000
    char* ws = (char*)d_ws;
    u64* keys   = (u64*)ws;                    ws += (size_t)total * 8;
    float* st   = (float*)ws;                  ws += (size_t)bs * NCLS * NPRED * 4;
    float4* pxy = (float4*)ws;                 ws += (size_t)total * 16;
    float* par  = (float*)ws;                  ws += (size_t)total * 4;
    float* out = (float*)d_out;

    const size_t need = (size_t)(ws - (char*)d_ws);
    if (ws_size >= need) {
        sig_transpose<<<bs * NCHUNK, 256, 0, stream>>>(logits, pboxes, st, pxy,
                                                       par, keys, total);
        topk_scatter<true><<<bs * NGT, 256, 0, stream>>>(logits, st, pboxes, pxy,
                                                         par, gboxes, glabels, keys);
    } else {
        init_keys<<<(total + 255) / 256, 256, 0, stream>>>(keys, total);
        topk_scatter<false><<<bs * NGT, 256, 0, stream>>>(logits, st, pboxes, pxy,
                                                          par, gboxes, glabels, keys);
    }
    finalize<<<(total + 255) / 256, 256, 0, stream>>>(glabels, keys, out, total);
}